// Round 1
// baseline (73.508 us; speedup 1.0000x reference)
//
#include <hip/hip_runtime.h>

#define NQ 8
#define NL 4
#define BATCH 4096

// State layout: one wave (64 lanes) per sample. Amp index a = (lane << 2) | r,
// r in 0..3. Wire i of the reference corresponds to bit (7 - i) of a
// (C-order flatten of shape (2,)*8: wire 0 is the MSB).
// Bits 2..7 of a are lane bits 0..5 (cross-lane via __shfl_xor);
// bits 0..1 are the per-lane register index.

__device__ __forceinline__ void apply_ry(float re[4], float im[4], int b,
                                         float c, float s, int lane) {
  if (b >= 2) {
    const int m = 1 << (b - 2);
    // bit=0 lane: new = c*mine - s*partner ; bit=1 lane: new = c*mine + s*partner
    const float ss = (lane & m) ? s : -s;
#pragma unroll
    for (int r = 0; r < 4; ++r) {
      float pr = __shfl_xor(re[r], m, 64);
      float pi = __shfl_xor(im[r], m, 64);
      re[r] = c * re[r] + ss * pr;
      im[r] = c * im[r] + ss * pi;
    }
  } else {
    const int p0a = 0, p1a = (b == 0) ? 1 : 2;        // pair 1
    const int p0b = (b == 0) ? 2 : 1, p1b = 3;        // pair 2
    {
      float n0r = c * re[p0a] - s * re[p1a], n1r = s * re[p0a] + c * re[p1a];
      float n0i = c * im[p0a] - s * im[p1a], n1i = s * im[p0a] + c * im[p1a];
      re[p0a] = n0r; re[p1a] = n1r; im[p0a] = n0i; im[p1a] = n1i;
    }
    {
      float n0r = c * re[p0b] - s * re[p1b], n1r = s * re[p0b] + c * re[p1b];
      float n0i = c * im[p0b] - s * im[p1b], n1i = s * im[p0b] + c * im[p1b];
      re[p0b] = n0r; re[p1b] = n1r; im[p0b] = n0i; im[p1b] = n1i;
    }
  }
}

__device__ __forceinline__ void apply_rz(float re[4], float im[4], int b,
                                         float c, float s, int lane) {
  // bit=0 amp *= (c - i s); bit=1 amp *= (c + i s)
  if (b >= 2) {
    const int m = 1 << (b - 2);
    const float ss = (lane & m) ? s : -s;
#pragma unroll
    for (int r = 0; r < 4; ++r) {
      float nr = re[r] * c - im[r] * ss;
      float ni = im[r] * c + re[r] * ss;
      re[r] = nr; im[r] = ni;
    }
  } else {
#pragma unroll
    for (int r = 0; r < 4; ++r) {
      const float ss = ((r >> b) & 1) ? s : -s;
      float nr = re[r] * c - im[r] * ss;
      float ni = im[r] * c + re[r] * ss;
      re[r] = nr; im[r] = ni;
    }
  }
}

__device__ __forceinline__ void cswap_pair(float re[4], float im[4],
                                           int p0, int p1, bool ctrl) {
  float r0 = re[p0], r1 = re[p1], i0 = im[p0], i1 = im[p1];
  re[p0] = ctrl ? r1 : r0; re[p1] = ctrl ? r0 : r1;
  im[p0] = ctrl ? i1 : i0; im[p1] = ctrl ? i0 : i1;
}

__device__ __forceinline__ void apply_cnot(float re[4], float im[4],
                                           int bc, int bt, int lane) {
  if (bt >= 2) {
    const int mt = 1 << (bt - 2);
#pragma unroll
    for (int r = 0; r < 4; ++r) {
      float pr = __shfl_xor(re[r], mt, 64);
      float pi = __shfl_xor(im[r], mt, 64);
      bool ctrl = (bc >= 2) ? (((lane >> (bc - 2)) & 1) != 0)
                            : (((r >> bc) & 1) != 0);
      re[r] = ctrl ? pr : re[r];
      im[r] = ctrl ? pi : im[r];
    }
  } else {
    // register-bit target: pairs along bit bt
    const int q0a = 0, q1a = (bt == 0) ? 1 : 2;
    const int q0b = (bt == 0) ? 2 : 1, q1b = 3;
    bool ca, cb;
    if (bc >= 2) {
      bool c = ((lane >> (bc - 2)) & 1) != 0;
      ca = c; cb = c;
    } else {
      ca = ((q0a >> bc) & 1) != 0;
      cb = ((q0b >> bc) & 1) != 0;
    }
    cswap_pair(re, im, q0a, q1a, ca);
    cswap_pair(re, im, q0b, q1b, cb);
  }
}

__global__ __launch_bounds__(256) void vqc_kernel(const float* __restrict__ x,
                                                  const float* __restrict__ w,
                                                  float* __restrict__ out) {
  const int wave = (int)((blockIdx.x * blockDim.x + threadIdx.x) >> 6);
  const int lane = (int)(threadIdx.x & 63);

  float re[4], im[4];
#pragma unroll
  for (int r = 0; r < 4; ++r) { re[r] = 0.f; im[r] = 0.f; }
  if (lane == 0) re[0] = 1.f;  // |0...0>

  // Angle encoding: RY(x_i) on wire i  (bit 7-i)
#pragma unroll
  for (int i = 0; i < NQ; ++i) {
    float t = x[wave * NQ + i] * 0.5f;
    float s, c;
    __sincosf(t, &s, &c);
    apply_ry(re, im, 7 - i, c, s, lane);
  }

  // Variational layers
#pragma unroll
  for (int l = 0; l < NL; ++l) {
    // CNOT ring, in order i = 0..7 (they don't all commute)
#pragma unroll
    for (int i = 0; i < NQ; ++i) {
      int bc = 7 - i;
      int bt = 7 - ((i + 1) & (NQ - 1));
      apply_cnot(re, im, bc, bt, lane);
    }
    // RY then RZ per wire
#pragma unroll
    for (int i = 0; i < NQ; ++i) {
      float ty = w[(l * NQ + i) * 2 + 0] * 0.5f;
      float tz = w[(l * NQ + i) * 2 + 1] * 0.5f;
      float sy, cy, sz, cz;
      __sincosf(ty, &sy, &cy);
      __sincosf(tz, &sz, &cz);
      apply_ry(re, im, 7 - i, cy, sy, lane);
      apply_rz(re, im, 7 - i, cz, sz, lane);
    }
  }

  // <Z_0> = P(bit7 = 0) - P(bit7 = 1); bit7 of amp index = lane bit 5
  float acc = 0.f;
#pragma unroll
  for (int r = 0; r < 4; ++r) acc += re[r] * re[r] + im[r] * im[r];
  acc = (lane & 32) ? -acc : acc;
#pragma unroll
  for (int m = 32; m; m >>= 1) acc += __shfl_xor(acc, m, 64);
  if (lane == 0) out[wave] = acc;
}

extern "C" void kernel_launch(void* const* d_in, const int* in_sizes, int n_in,
                              void* d_out, int out_size, void* d_ws, size_t ws_size,
                              hipStream_t stream) {
  const float* x = (const float*)d_in[0];   // (4096, 8) f32
  const float* w = (const float*)d_in[1];   // (4, 8, 2) f32
  float* out = (float*)d_out;               // (4096,) f32
  (void)in_sizes; (void)n_in; (void)out_size; (void)d_ws; (void)ws_size;

  // one wave per sample: 4096 waves = 1024 blocks x 256 threads
  dim3 grid(BATCH / 4), block(256);
  hipLaunchKernelGGL(vqc_kernel, grid, block, 0, stream, x, w, out);
}